// Round 1
// baseline (500.536 us; speedup 1.0000x reference)
//
#include <hip/hip_runtime.h>
#include <hip/hip_bf16.h>
#include <stdint.h>

typedef short short8 __attribute__((ext_vector_type(8)));
typedef float f32x4 __attribute__((ext_vector_type(4)));

__device__ __forceinline__ uint32_t f32_to_bf16_rne(float f) {
    uint32_t u = __builtin_bit_cast(uint32_t, f);
    uint32_t r = u + 0x7FFFu + ((u >> 16) & 1u);
    return r >> 16;
}

// ---------------------------------------------------------------------------
// Pre-kernel: Wt[l][o][i] = bf16(w_l[i][o])  (transpose so B-fragments are
// contiguous-in-i 16B loads). 4 * 128 * 128 bf16 = 128 KB in d_ws.
// ---------------------------------------------------------------------------
__global__ void conv_weights(const float* __restrict__ w0, const float* __restrict__ w1,
                             const float* __restrict__ w2, const float* __restrict__ w3,
                             uint16_t* __restrict__ wt) {
    int idx = blockIdx.x * 256 + threadIdx.x;   // 0 .. 65535
    int l = idx >> 14;
    int o = (idx >> 7) & 127;
    int i = idx & 127;
    const float* w = (l == 0) ? w0 : (l == 1) ? w1 : (l == 2) ? w2 : w3;
    wt[idx] = (uint16_t)f32_to_bf16_rne(w[i * 128 + o]);
}

// ---------------------------------------------------------------------------
// Main kernel: block = 256 thr = 4 waves, one 16-row n-tile.
// LDS x-tile layout (bf16, swizzled):
//   off(nn,c,i) = nn*4096 + ((c*256 + (i>>3)*16) ^ (((nn^c)&7)<<4)) + (i&7)*2
// Wave w owns channels c0 = 4w .. 4w+3  -> float4 output stores (4 consec c).
// MFMA 16x16x32 bf16: A row=lane&15(=nn), k=(lane>>4)*8+j(=i); B col=lane&15(=o);
// D col=lane&15(=o), row=(lane>>4)*4+reg(=nn).
// ---------------------------------------------------------------------------
__global__ void isl_kernel(const float* __restrict__ x,
                           const uint16_t* __restrict__ wt,
                           float* __restrict__ out) {
    __shared__ uint8_t lds[65536];
    const int tid = threadIdx.x;
    const int n0 = blockIdx.x * 16;

    // ---- stage x[n0..n0+15][0..127][0..15] -> LDS bf16 [nn][c][i] (swizzled)
    {
        const int c  = tid & 15;
        const int nn = tid >> 4;
        const float* xrow = x + (size_t)(n0 + nn) * 2048 + c;
        const uint32_t base = (uint32_t)nn * 4096;
        const uint32_t swz  = ((uint32_t)((nn ^ c) & 7)) << 4;
        #pragma unroll 8
        for (int i = 0; i < 128; i += 2) {
            float f0 = xrow[(size_t)i * 16];
            float f1 = xrow[(size_t)(i + 1) * 16];
            uint32_t p = f32_to_bf16_rne(f0) | (f32_to_bf16_rne(f1) << 16);
            uint32_t off = base + (((uint32_t)(c * 256 + (i >> 3) * 16)) ^ swz) + (i & 7) * 2;
            *(uint32_t*)(lds + off) = p;
        }
    }
    __syncthreads();

    const int lane  = tid & 63;
    const int wid   = tid >> 6;
    const int c0    = wid * 4;        // this wave's first channel
    const int row16 = lane & 15;      // A-row (nn) / B-col (o) / D-col (o)
    const int kgrp  = lane >> 4;      // 0..3

    // ---- A fragments: a[cc][k] = x[nn=row16][i = k*32 + kgrp*8 + j][c0+cc]
    short8 a[4][4];
    #pragma unroll
    for (int cc = 0; cc < 4; ++cc) {
        const int c = c0 + cc;
        const uint32_t swz = ((uint32_t)((row16 ^ c) & 7)) << 4;
        #pragma unroll
        for (int k = 0; k < 4; ++k) {
            const int i0 = k * 32 + kgrp * 8;
            const uint32_t off = (uint32_t)row16 * 4096 +
                (((uint32_t)(c * 256 + (i0 >> 3) * 16)) ^ swz);
            a[cc][k] = *(const short8*)(lds + off);
        }
    }

    // ---- loop over o-tiles; per c: 4 MFMAs (K=128); B frags from L2-resident wt
    for (int ot = 0; ot < 8; ++ot) {
        f32x4 acc[4];
        short8 b[4];
        int lcur = -1;
        #pragma unroll
        for (int cc = 0; cc < 4; ++cc) {
            const int c = c0 + cc;
            const int l = (c >= 1) + (c >= 4) + (c >= 9);   // degree of channel c
            if (l != lcur) {
                lcur = l;
                const uint16_t* wb = wt + (size_t)l * 16384 +
                                     (size_t)(ot * 16 + row16) * 128 + kgrp * 8;
                #pragma unroll
                for (int k = 0; k < 4; ++k)
                    b[k] = *(const short8*)(wb + k * 32);
            }
            f32x4 acc_ = {0.f, 0.f, 0.f, 0.f};
            #pragma unroll
            for (int k = 0; k < 4; ++k)
                acc_ = __builtin_amdgcn_mfma_f32_16x16x32_bf16(a[cc][k], b[k], acc_, 0, 0, 0);
            acc[cc] = acc_;
        }
        // ---- store: lane packs its 4 channels -> one dwordx4 per D-row
        const int o = ot * 16 + row16;
        #pragma unroll
        for (int r = 0; r < 4; ++r) {
            const int n = n0 + kgrp * 4 + r;
            f32x4 v = {acc[0][r], acc[1][r], acc[2][r], acc[3][r]};
            *(f32x4*)(out + (size_t)n * 2048 + (size_t)o * 16 + c0) = v;
        }
    }
}

extern "C" void kernel_launch(void* const* d_in, const int* in_sizes, int n_in,
                              void* d_out, int out_size, void* d_ws, size_t ws_size,
                              hipStream_t stream) {
    const float* x  = (const float*)d_in[0];
    const float* w0 = (const float*)d_in[1];
    const float* w1 = (const float*)d_in[2];
    const float* w2 = (const float*)d_in[3];
    const float* w3 = (const float*)d_in[4];
    uint16_t* wt = (uint16_t*)d_ws;          // 128 KB scratch
    float* out = (float*)d_out;

    conv_weights<<<256, 256, 0, stream>>>(w0, w1, w2, w3, wt);
    isl_kernel<<<6250, 256, 0, stream>>>(x, wt, out);   // 6250 * 16 = 100000 rows
}

// Round 2
// 489.164 us; speedup vs baseline: 1.0232x; 1.0232x over previous
//
#include <hip/hip_runtime.h>
#include <hip/hip_bf16.h>
#include <stdint.h>

typedef short short8 __attribute__((ext_vector_type(8)));
typedef float f32x4 __attribute__((ext_vector_type(4)));

__device__ __forceinline__ uint32_t f32_to_bf16_rne(float f) {
    uint32_t u = __builtin_bit_cast(uint32_t, f);
    uint32_t r = u + 0x7FFFu + ((u >> 16) & 1u);
    return r >> 16;
}
__device__ __forceinline__ uint32_t pack2(float lo, float hi) {
    return f32_to_bf16_rne(lo) | (f32_to_bf16_rne(hi) << 16);
}

// ---------------------------------------------------------------------------
// Pre-kernel: Wt[l][o][i] = bf16(w_l[i][o])  (transpose so B-fragments are
// contiguous-in-i 16B loads). 4 * 128 * 128 bf16 = 128 KB in d_ws.
// ---------------------------------------------------------------------------
__global__ void conv_weights(const float* __restrict__ w0, const float* __restrict__ w1,
                             const float* __restrict__ w2, const float* __restrict__ w3,
                             uint16_t* __restrict__ wt) {
    int idx = blockIdx.x * 256 + threadIdx.x;   // 0 .. 65535
    int l = idx >> 14;
    int o = (idx >> 7) & 127;
    int i = idx & 127;
    const float* w = (l == 0) ? w0 : (l == 1) ? w1 : (l == 2) ? w2 : w3;
    wt[idx] = (uint16_t)f32_to_bf16_rne(w[i * 128 + o]);
}

// ---------------------------------------------------------------------------
// Main kernel: block = 256 thr = 4 waves, one 16-row n-tile.
// LDS x-tile layout (bf16, swizzled):
//   off(nn,c,i) = nn*4096 + ((c*256 + (i>>3)*16) ^ (((nn^c)&7)<<4)) + (i&7)*2
// Staging: thread (nn=tid>>4, cq=tid&3, isub=(tid>>2)&3) loads float4 pairs
// (c-contiguous, 16B/lane, fully dense 64B lines), packs bf16 pairs along i,
// ds_write_b32 with 2-way-max bank aliasing.
// MFMA 16x16x32 bf16: A row=lane&15(=nn), k=(lane>>4)*8+j(=i); B col=lane&15(=o);
// D col=lane&15(=o), row=(lane>>4)*4+reg(=nn).
// ---------------------------------------------------------------------------
__global__ void __launch_bounds__(256, 2)
isl_kernel(const float* __restrict__ x,
           const uint16_t* __restrict__ wt,
           float* __restrict__ out) {
    __shared__ uint8_t lds[65536];
    const int tid = threadIdx.x;
    const int n0 = blockIdx.x * 16;

    // ---- stage x[n0..n0+15][0..127][0..15] -> LDS bf16 [nn][c][i] (swizzled)
    {
        const int nn   = tid >> 4;        // 0..15
        const int cq   = tid & 3;         // c-quad: c = cq*4 + cc
        const int isub = (tid >> 2) & 3;  // i = t*8 + isub*2 (+1)
        const float* xb = x + (size_t)(n0 + nn) * 2048 + cq * 4;
        const uint32_t base = (uint32_t)nn * 4096 + (uint32_t)isub * 4;
        #pragma unroll
        for (int b = 0; b < 2; ++b) {
            f32x4 v0[8], v1[8];
            #pragma unroll
            for (int u = 0; u < 8; ++u) {
                const int i = (b * 8 + u) * 8 + isub * 2;
                v0[u] = *(const f32x4*)(xb + (size_t)i * 16);
                v1[u] = *(const f32x4*)(xb + (size_t)(i + 1) * 16);
            }
            #pragma unroll
            for (int u = 0; u < 8; ++u) {
                const int t = b * 8 + u;
                #pragma unroll
                for (int cc = 0; cc < 4; ++cc) {
                    const int c = cq * 4 + cc;
                    const uint32_t off = base +
                        (((uint32_t)(c * 256 + t * 16)) ^ (((uint32_t)((nn ^ c) & 7)) << 4));
                    *(uint32_t*)(lds + off) = pack2(v0[u][cc], v1[u][cc]);
                }
            }
        }
    }
    __syncthreads();

    const int lane  = tid & 63;
    const int wid   = tid >> 6;
    const int c0    = wid * 4;        // this wave's first channel
    const int row16 = lane & 15;      // A-row (nn) / B-col (o) / D-col (o)
    const int kgrp  = lane >> 4;      // 0..3

    // ---- A fragments: a[cc][k] = x[nn=row16][i = k*32 + kgrp*8 + j][c0+cc]
    short8 a[4][4];
    #pragma unroll
    for (int cc = 0; cc < 4; ++cc) {
        const int c = c0 + cc;
        const uint32_t swz = ((uint32_t)((row16 ^ c) & 7)) << 4;
        #pragma unroll
        for (int k = 0; k < 4; ++k) {
            const int i0 = k * 32 + kgrp * 8;
            const uint32_t off = (uint32_t)row16 * 4096 +
                (((uint32_t)(c * 256 + (i0 >> 3) * 16)) ^ swz);
            a[cc][k] = *(const short8*)(lds + off);
        }
    }

    // ---- loop over o-tiles; per c: 4 MFMAs (K=128); B frags from L2-resident wt
    for (int ot = 0; ot < 8; ++ot) {
        f32x4 acc[4];
        short8 b[4];
        int lcur = -1;
        #pragma unroll
        for (int cc = 0; cc < 4; ++cc) {
            const int c = c0 + cc;
            const int l = (c >= 1) + (c >= 4) + (c >= 9);   // degree of channel c
            if (l != lcur) {
                lcur = l;
                const uint16_t* wb = wt + (size_t)l * 16384 +
                                     (size_t)(ot * 16 + row16) * 128 + kgrp * 8;
                #pragma unroll
                for (int k = 0; k < 4; ++k)
                    b[k] = *(const short8*)(wb + k * 32);
            }
            f32x4 acc_ = {0.f, 0.f, 0.f, 0.f};
            #pragma unroll
            for (int k = 0; k < 4; ++k)
                acc_ = __builtin_amdgcn_mfma_f32_16x16x32_bf16(a[cc][k], b[k], acc_, 0, 0, 0);
            acc[cc] = acc_;
        }
        // ---- store: lane packs its 4 channels -> one dwordx4 per D-row
        const int o = ot * 16 + row16;
        #pragma unroll
        for (int r = 0; r < 4; ++r) {
            const int n = n0 + kgrp * 4 + r;
            f32x4 v = {acc[0][r], acc[1][r], acc[2][r], acc[3][r]};
            *(f32x4*)(out + (size_t)n * 2048 + (size_t)o * 16 + c0) = v;
        }
    }
}

extern "C" void kernel_launch(void* const* d_in, const int* in_sizes, int n_in,
                              void* d_out, int out_size, void* d_ws, size_t ws_size,
                              hipStream_t stream) {
    const float* x  = (const float*)d_in[0];
    const float* w0 = (const float*)d_in[1];
    const float* w1 = (const float*)d_in[2];
    const float* w2 = (const float*)d_in[3];
    const float* w3 = (const float*)d_in[4];
    uint16_t* wt = (uint16_t*)d_ws;          // 128 KB scratch
    float* out = (float*)d_out;

    conv_weights<<<256, 256, 0, stream>>>(w0, w1, w2, w3, wt);
    isl_kernel<<<6250, 256, 0, stream>>>(x, wt, out);   // 6250 * 16 = 100000 rows
}

// Round 3
// 466.254 us; speedup vs baseline: 1.0735x; 1.0491x over previous
//
#include <hip/hip_runtime.h>
#include <hip/hip_bf16.h>
#include <stdint.h>

typedef short short8 __attribute__((ext_vector_type(8)));
typedef float f32x4 __attribute__((ext_vector_type(4)));
typedef uint32_t u32x4 __attribute__((ext_vector_type(4)));

#define NTILES 6250   // 100000 / 16
#define NBLK   256

__device__ __forceinline__ uint32_t f32_to_bf16_rne(float f) {
    uint32_t u = __builtin_bit_cast(uint32_t, f);
    uint32_t r = u + 0x7FFFu + ((u >> 16) & 1u);
    return r >> 16;
}
__device__ __forceinline__ uint32_t pack2(float lo, float hi) {
    return f32_to_bf16_rne(lo) | (f32_to_bf16_rne(hi) << 16);
}

// ---------------------------------------------------------------------------
// Pre-kernel: Wt[l][o][i] = bf16(w_l[i][o])  (transposed so B-fragments are
// contiguous-in-i 16B loads). 4 * 128 * 128 bf16 = 128 KB in d_ws.
// ---------------------------------------------------------------------------
__global__ void conv_weights(const float* __restrict__ w0, const float* __restrict__ w1,
                             const float* __restrict__ w2, const float* __restrict__ w3,
                             uint16_t* __restrict__ wt) {
    int idx = blockIdx.x * 256 + threadIdx.x;   // 0 .. 65535
    int l = idx >> 14;
    int o = (idx >> 7) & 127;
    int i = idx & 127;
    const float* w = (l == 0) ? w0 : (l == 1) ? w1 : (l == 2) ? w2 : w3;
    wt[idx] = (uint16_t)f32_to_bf16_rne(w[i * 128 + o]);
}

// ---------------------------------------------------------------------------
// Main kernel: 256 persistent blocks x 512 thr (8 waves), 128 KB LDS as two
// 64 KB bf16 tile buffers. Software pipeline per 16-row n-tile:
//   write LDS[buf] from regs(t) -> issue loads regs(t+1) ->
//   s_waitcnt lgkmcnt(0); s_barrier (vmcnt NOT drained!) -> compute(t)
// LDS x-tile layout (bf16, swizzled):
//   off(nn,c,i) = nn*4096 + ((c*256 + (i>>3)*16) ^ (((nn^c)&7)<<4)) + (i&7)*2
// Wave w owns o-tile ot=w (all 16 channels) -> each lane stores the full
// contiguous out[n][o][0..15] (4 x dwordx4) => full-line writes, no RMW amp.
// MFMA 16x16x32 bf16: A row=lane&15(=nn), k=(lane>>4)*8+j(=i); B col=lane&15(=o);
// D col=lane&15(=o), row=(lane>>4)*4+reg(=nn).
// ---------------------------------------------------------------------------
__global__ void __launch_bounds__(512, 2)
isl_kernel(const float* __restrict__ x,
           const uint16_t* __restrict__ wt,
           float* __restrict__ out) {
    __shared__ uint8_t lds[2][65536];
    const int tid = threadIdx.x;

    // staging coords: thread -> (row nn, i-block isub, c-quad scq)
    const int snn   = tid >> 5;        // 0..15
    const int sisub = (tid >> 2) & 7;  // i = sisub*16 + u
    const int scq   = tid & 3;         // c = scq*4 + cc

    f32x4 v[16];  // in-flight staging tile: 16 x float4 = 64 VGPR

    // compute coords
    const int lane  = tid & 63;
    const int wid   = tid >> 6;     // 0..7 = this wave's o-tile
    const int row16 = lane & 15;    // A-row (nn) / B-col & D-col (o)
    const int kgrp  = lane >> 4;    // 0..3

    int t   = blockIdx.x;
    int buf = 0;

    // ---- prologue: issue loads for first tile
    {
        const float* xb = x + (size_t)(t * 16 + snn) * 2048 + sisub * 256 + scq * 4;
        #pragma unroll
        for (int u = 0; u < 16; ++u)
            v[u] = *(const f32x4*)(xb + u * 16);
    }

    while (true) {
        // ---- write LDS[buf] from regs (vmcnt waits inserted by compiler)
        {
            uint8_t* L = lds[buf];
            const uint32_t base = (uint32_t)snn * 4096;
            #pragma unroll
            for (int cc = 0; cc < 4; ++cc) {
                const int c = scq * 4 + cc;
                const uint32_t swz = ((uint32_t)((snn ^ c) & 7)) << 4;
                #pragma unroll
                for (int g = 0; g < 2; ++g) {   // i-groups of 8: i = sisub*16 + g*8 + 0..7
                    u32x4 p;
                    #pragma unroll
                    for (int q = 0; q < 4; ++q)
                        p[q] = pack2(v[g * 8 + q * 2][cc], v[g * 8 + q * 2 + 1][cc]);
                    const uint32_t off = base +
                        (((uint32_t)(c * 256 + (sisub * 2 + g) * 16)) ^ swz);
                    *(u32x4*)(L + off) = p;
                }
            }
        }

        // ---- issue next tile's loads BEFORE the barrier (stay in flight)
        const int tn = t + NBLK;
        const bool more = (tn < NTILES);
        if (more) {
            const float* xb = x + (size_t)(tn * 16 + snn) * 2048 + sisub * 256 + scq * 4;
            #pragma unroll
            for (int u = 0; u < 16; ++u)
                v[u] = *(const f32x4*)(xb + u * 16);
        }

        // ---- barrier WITHOUT vmcnt drain: only LDS writes must be visible
        asm volatile("s_waitcnt lgkmcnt(0)" ::: "memory");
        __builtin_amdgcn_s_barrier();
        asm volatile("" ::: "memory");

        // ---- compute tile t from LDS[buf]
        {
            const uint8_t* L = lds[buf];
            float* outb = out + (size_t)(t * 16) * 2048 + (size_t)(wid * 16 + row16) * 16;
            int lcur = -1;
            short8 b[4];
            #pragma unroll
            for (int ccq = 0; ccq < 4; ++ccq) {
                f32x4 acc4[4];
                #pragma unroll
                for (int c4 = 0; c4 < 4; ++c4) {
                    const int c = ccq * 4 + c4;
                    const int l = (c >= 1) + (c >= 4) + (c >= 9);
                    if (l != lcur) {   // compile-time foldable (unrolled chain)
                        lcur = l;
                        const uint16_t* wb = wt + (size_t)l * 16384 +
                                             (size_t)(wid * 16 + row16) * 128 + kgrp * 8;
                        #pragma unroll
                        for (int k = 0; k < 4; ++k)
                            b[k] = *(const short8*)(wb + k * 32);
                    }
                    const uint32_t swz = ((uint32_t)((row16 ^ c) & 7)) << 4;
                    f32x4 acc = {0.f, 0.f, 0.f, 0.f};
                    #pragma unroll
                    for (int k = 0; k < 4; ++k) {
                        const uint32_t off = (uint32_t)row16 * 4096 +
                            (((uint32_t)(c * 256 + (k * 4 + kgrp) * 16)) ^ swz);
                        short8 a = *(const short8*)(L + off);
                        acc = __builtin_amdgcn_mfma_f32_16x16x32_bf16(a, b[k], acc, 0, 0, 0);
                    }
                    acc4[c4] = acc;
                }
                // lane writes 4 consecutive c's for its (n, o): full-line coverage
                #pragma unroll
                for (int r = 0; r < 4; ++r) {
                    f32x4 o4 = {acc4[0][r], acc4[1][r], acc4[2][r], acc4[3][r]};
                    *(f32x4*)(outb + (size_t)(kgrp * 4 + r) * 2048 + ccq * 4) = o4;
                }
            }
        }

        if (!more) break;
        t = tn;
        buf ^= 1;
    }
}

extern "C" void kernel_launch(void* const* d_in, const int* in_sizes, int n_in,
                              void* d_out, int out_size, void* d_ws, size_t ws_size,
                              hipStream_t stream) {
    const float* x  = (const float*)d_in[0];
    const float* w0 = (const float*)d_in[1];
    const float* w1 = (const float*)d_in[2];
    const float* w2 = (const float*)d_in[3];
    const float* w3 = (const float*)d_in[4];
    uint16_t* wt = (uint16_t*)d_ws;          // 128 KB scratch
    float* out = (float*)d_out;

    conv_weights<<<256, 256, 0, stream>>>(w0, w1, w2, w3, wt);
    isl_kernel<<<NBLK, 512, 0, stream>>>(x, wt, out);
}